// Round 15
// baseline (80.378 us; speedup 1.0000x reference)
//
#include <hip/hip_runtime.h>
#include <hip/hip_bf16.h>
#include <stdint.h>
#include <stddef.h>

#define NSEQ  4096
#define DM    1024
#define NHEAD 16
#define DHEAD 64
#define WIN   64

using short8 = __attribute__((ext_vector_type(8))) short;
using f32x4  = __attribute__((ext_vector_type(4))) float;

#define GLOBAL_AS __attribute__((address_space(1)))
#define LDS_AS    __attribute__((address_space(3)))

__device__ __forceinline__ unsigned short f2bf(float f) {
  union { float f; unsigned int u; } v; v.f = f;
  unsigned int r = v.u + 0x7FFFu + ((v.u >> 16) & 1u);
  return (unsigned short)(r >> 16);
}

__device__ __forceinline__ void gload_lds16(void* lds, const void* g) {
  __builtin_amdgcn_global_load_lds((const GLOBAL_AS unsigned int*)g,
                                   (LDS_AS unsigned int*)lds, 16, 0, 0);
}

// ---------------- fused fp32 -> bf16 conversion (x | w_qkv | w_out) --------
#define NX4 1048576
#define NW4 786432
__global__ void cvt_all(const float* __restrict__ x,
                        const float* __restrict__ wqkv,
                        const float* __restrict__ wout,
                        unsigned short* __restrict__ dst) {
  int i = blockIdx.x * blockDim.x + threadIdx.x;   // group of 4 floats
  float4 f;
  if (i < NX4)            f = ((const float4*)x)[i];
  else if (i < NX4 + NW4) f = ((const float4*)wqkv)[i - NX4];
  else                    f = ((const float4*)wout)[i - (NX4 + NW4)];
  ushort4 o;
  o.x = f2bf(f.x); o.y = f2bf(f.y); o.z = f2bf(f.z); o.w = f2bf(f.w);
  ((ushort4*)dst)[i] = o;
}

// ============ QKV GEMM: 128x384 tile, BK=64, 2-phase/tile, 24 MFMA/barrier =
// (unchanged from round 14 — best validated variant)
__global__ __launch_bounds__(512, 1)
void gemm_qkv(const unsigned short* __restrict__ A,
              const unsigned short* __restrict__ B,
              const float* __restrict__ bias,
              unsigned short* __restrict__ qo,
              unsigned short* __restrict__ ko,
              unsigned short* __restrict__ vo) {
  __shared__ short lds[65536];   // 128 KB: buf b at b*32768 {A:8192 | B:24576}

  const int bm = blockIdx.x >> 3;    // M/128 = 32
  const int bn = blockIdx.x & 7;     // N/384 = 8
  const int m0 = bm << 7, n0 = bn * 384;
  const int tid = threadIdx.x, w = tid >> 6, l = tid & 63;
  const int wr = w >> 2, wc = w & 3;
  const int l15 = l & 15, l4 = l >> 4;
  const int srow = l >> 2;
  const int skel = ((l & 3) << 3) ^ ((l >= 32) << 4);          // inv-swz global k
  const int roff = l15 * 32 + ((l4 * 8) ^ ((l15 >= 8) * 16));  // swz read off

  f32x4 acc[4][6] = {};

  auto stageA = [&](int j) {
    const int base = (j & 1) * 32768;
#pragma unroll
    for (int r = 0; r < 2; ++r) {
      const int c = r * 8 + w;
      gload_lds16(&lds[base + c * 512 + l * 8],
                  A + (size_t)(m0 + (c >> 1) * 16 + srow) * 1024
                    + (j << 6) + (c & 1) * 32 + skel);
    }
  };
  auto stageB = [&](int j, int qk) {
    const int base = (j & 1) * 32768 + 8192 + qk * 12288;
#pragma unroll
    for (int r = 0; r < 3; ++r) {
      const int c = r * 8 + w;
      gload_lds16(&lds[base + c * 512 + l * 8],
                  B + (size_t)(n0 + c * 16 + srow) * 1024
                    + (j << 6) + qk * 32 + skel);
    }
  };

  auto ldfrag = [&](short8* af, short8* bf, int buf, int qk) {
    const short* Ah = &lds[buf];
    const short* Bh = &lds[buf + 8192 + qk * 12288];
#pragma unroll
    for (int i = 0; i < 4; ++i)
      af[i] = *(const short8*)&Ah[((wr * 4 + i) * 2 + qk) * 512 + roff];
#pragma unroll
    for (int ni = 0; ni < 6; ++ni)
      bf[ni] = *(const short8*)&Bh[(wc * 6 + ni) * 512 + roff];
  };
  auto mfma24 = [&](const short8* af, const short8* bf) {
    __builtin_amdgcn_s_setprio(1);
#pragma unroll
    for (int i = 0; i < 4; ++i)
#pragma unroll
      for (int ni = 0; ni < 6; ++ni)
        acc[i][ni] = __builtin_amdgcn_mfma_f32_16x16x32_bf16(
            af[i], bf[ni], acc[i][ni], 0, 0, 0);
    __builtin_amdgcn_s_setprio(0);
  };

  // prologue
  stageA(0); stageB(0, 0); stageB(0, 1); stageB(1, 0);
  asm volatile("s_waitcnt vmcnt(3)" ::: "memory");   // Bk0(1) stays in flight
  __builtin_amdgcn_s_barrier();

  const int NT = 16;   // 1024 / 64
  short8 af[4], bf[6];
  for (int j = 0; j < NT; ++j) {
    const int buf = (j & 1) * 32768;
    // ---- p0 (qk=0) ----
    ldfrag(af, bf, buf, 0);
    if (j + 1 < NT) { stageA(j + 1); stageB(j + 1, 1); }
    __builtin_amdgcn_s_barrier();
    mfma24(af, bf);
    // ---- p1 (qk=1) ----
    ldfrag(af, bf, buf, 1);
    if (j + 2 < NT) {
      stageB(j + 2, 0);
      asm volatile("s_waitcnt vmcnt(3)" ::: "memory");  // {A,Bk1,Bk0}(j+1) in
    } else if (j + 1 < NT) {
      asm volatile("s_waitcnt vmcnt(0)" ::: "memory");
    }
    __builtin_amdgcn_s_barrier();
    mfma24(af, bf);
  }

  // epilogue: scatter to Q (scaled), K, V^T  (region per 16-col fragment)
#pragma unroll
  for (int ni = 0; ni < 6; ++ni) {
    const int n  = n0 + wc * 96 + ni * 16 + l15;
    const float bv = bias[n];
    const int region = n >> 10;
#pragma unroll
    for (int mi = 0; mi < 4; ++mi) {
      const int mb = m0 + wr * 64 + mi * 16 + l4 * 4;
      if (region == 0) {
        const int h = (n >> 6) & 15, d = n & 63;
#pragma unroll
        for (int r = 0; r < 4; ++r)
          qo[((size_t)(h * NSEQ + mb + r)) * DHEAD + d] =
              f2bf((acc[mi][ni][r] + bv) * 0.125f);
      } else if (region == 1) {
        const int nn = n - 1024;
        const int h = nn >> 6, d = nn & 63;
#pragma unroll
        for (int r = 0; r < 4; ++r)
          ko[((size_t)(h * NSEQ + mb + r)) * DHEAD + d] =
              f2bf(acc[mi][ni][r] + bv);
      } else {
        const int nn = n - 2048;    // = h*64 + d
        ushort4 pk;
        pk.x = f2bf(acc[mi][ni][0] + bv);
        pk.y = f2bf(acc[mi][ni][1] + bv);
        pk.z = f2bf(acc[mi][ni][2] + bv);
        pk.w = f2bf(acc[mi][ni][3] + bv);
        *(ushort4*)&vo[(size_t)nn * NSEQ + mb] = pk;   // V^T: [h*64+d][m]
      }
    }
  }
}

// ====== out-proj GEMM: 64x128 tile, BK=64, 2-buf, 2 blocks/CU ==============
// R13 kernel + NEW: C-store via LDS transpose bounce -> float4 full-row
// stores (8 vector stores/lane instead of 32 scalar 64-B-segment stores).
__global__ __launch_bounds__(256)
void gemm_op(const unsigned short* __restrict__ A,
             const unsigned short* __restrict__ B,
             const float* __restrict__ bias,
             float* __restrict__ Cf) {
  __shared__ short lds[2][12288];   // 24 KB/buf: A 4096 | B 8192 shorts

  const int wg = (blockIdx.x & 7) * 64 + (blockIdx.x >> 3);  // XCD chunks
  const int bm = wg >> 3;           // 64 m-tiles (64 rows)
  const int bn = wg & 7;            // 8 n-tiles (128 cols)
  const int m0 = bm << 6, n0 = bn << 7;
  const int tid = threadIdx.x, w = tid >> 6, l = tid & 63;
  const int wr = w >> 1, wc = w & 1;
  const int l15 = l & 15, l4 = l >> 4;
  const int srow = l >> 2;
  const int skel = ((l & 3) << 3) ^ ((l >= 32) << 4);
  const int roff = l15 * 32 + ((l4 * 8) ^ ((l15 >= 8) * 16));

  f32x4 acc[2][4] = {};
  const int NT = 16;

  auto stage = [&](int t) {
    const int buf = t & 1;
    const int kb  = t << 6;
#pragma unroll
    for (int r = 0; r < 2; ++r) {          // A: 8 subtiles
      const int c = r * 4 + w;
      gload_lds16(&lds[buf][c * 512 + l * 8],
                  A + (size_t)(m0 + (c >> 1) * 16 + srow) * 1024
                    + kb + (c & 1) * 32 + skel);
    }
#pragma unroll
    for (int r = 0; r < 4; ++r) {          // B: 16 subtiles
      const int c = r * 4 + w;
      gload_lds16(&lds[buf][4096 + c * 512 + l * 8],
                  B + (size_t)(n0 + (c >> 1) * 16 + srow) * 1024
                    + kb + (c & 1) * 32 + skel);
    }
  };

  stage(0);
  for (int t = 0; t < NT; ++t) {
    __syncthreads();                    // full drain -> stage(t) visible
    if (t + 1 < NT) stage(t + 1);       // other buf (WAR-safe after barrier)
    const short* Ab = &lds[t & 1][0];
    const short* Bb = &lds[t & 1][4096];
    short8 af[2][2], bf[4][2];
#pragma unroll
    for (int mi = 0; mi < 2; ++mi)
#pragma unroll
      for (int kk = 0; kk < 2; ++kk)
        af[mi][kk] = *(const short8*)&Ab[((wr * 2 + mi) * 2 + kk) * 512 + roff];
#pragma unroll
    for (int ni = 0; ni < 4; ++ni)
#pragma unroll
      for (int kk = 0; kk < 2; ++kk)
        bf[ni][kk] = *(const short8*)&Bb[((wc * 4 + ni) * 2 + kk) * 512 + roff];
    __builtin_amdgcn_s_setprio(1);
#pragma unroll
    for (int kk = 0; kk < 2; ++kk)
#pragma unroll
      for (int mi = 0; mi < 2; ++mi)
#pragma unroll
        for (int ni = 0; ni < 4; ++ni)
          acc[mi][ni] = __builtin_amdgcn_mfma_f32_16x16x32_bf16(
              af[mi][kk], bf[ni][kk], acc[mi][ni], 0, 0, 0);
    __builtin_amdgcn_s_setprio(0);
  }

  // ---- C-store bounce: acc -> per-wave LDS f32 tile (stride 66, bank-
  // rotated) -> full-row float4 stores. Barrier first: all waves' LDS
  // reads from the main loop are done before aliasing the buffers.
  __syncthreads();
  float* Cl = ((float*)&lds[0][0]) + w * 2112;   // 32 rows x 66 floats/wave
#pragma unroll
  for (int ni = 0; ni < 4; ++ni) {
    const int n  = n0 + wc * 64 + ni * 16 + l15;
    const float bv = bias[n];
#pragma unroll
    for (int mi = 0; mi < 2; ++mi)
#pragma unroll
      for (int r = 0; r < 4; ++r)
        Cl[(mi * 16 + l4 * 4 + r) * 66 + ni * 16 + l15] = acc[mi][ni][r] + bv;
  }
  // wave-synchronous LDS round-trip (compiler inserts lgkmcnt ordering)
#pragma unroll
  for (int p = 0; p < 8; ++p) {
    const int idx = p * 64 + l;
    const int row = idx >> 4;          // 0..31
    const int c4  = (idx & 15) * 4;    // 0..60
    *(float4*)&Cf[(size_t)(m0 + wr * 32 + row) * DM + n0 + wc * 64 + c4] =
        *(const float4*)&Cl[row * 66 + c4];
  }
}

// ---------------- windowed causal attention: 6-tile trim + vector O-store --
__global__ __launch_bounds__(256)
void attn_kernel(const unsigned short* __restrict__ Qb,
                 const unsigned short* __restrict__ Kb,
                 const unsigned short* __restrict__ Vt,
                 unsigned short* __restrict__ att) {
  __shared__ short Pl[4][16][136];
  const int h  = blockIdx.x >> 6;
  const int q0 = (blockIdx.x & 63) << 6;
  const int w  = threadIdx.x >> 6;
  const int l  = threadIdx.x & 63;
  const int l15 = l & 15, l4 = l >> 4;
  const int qw = q0 + w * 16;
  const int tb = w & ~1;

  const unsigned short* Qh = Qb + (size_t)h * NSEQ * DHEAD;
  const unsigned short* Kh = Kb + (size_t)h * NSEQ * DHEAD;
  const unsigned short* Vh = Vt + (size_t)h * DHEAD * NSEQ;

  short8 aq[2];
  {
    const int qrow = qw + l15;
    aq[0] = *(const short8*)&Qh[(size_t)qrow * DHEAD + l4 * 8];
    aq[1] = *(const short8*)&Qh[(size_t)qrow * DHEAD + 32 + l4 * 8];
  }

  f32x4 s[6] = {};
#pragma unroll
  for (int tt = 0; tt < 6; ++tt) {
    int j  = q0 - 64 + (tb + tt) * 16 + l15;
    int jc = j < 0 ? 0 : j;
    short8 b0 = *(const short8*)&Kh[(size_t)jc * DHEAD + l4 * 8];
    short8 b1 = *(const short8*)&Kh[(size_t)jc * DHEAD + 32 + l4 * 8];
    s[tt] = __builtin_amdgcn_mfma_f32_16x16x32_bf16(aq[0], b0, s[tt], 0, 0, 0);
    s[tt] = __builtin_amdgcn_mfma_f32_16x16x32_bf16(aq[1], b1, s[tt], 0, 0, 0);
  }

  float rmax[4] = {-3e38f, -3e38f, -3e38f, -3e38f};
#pragma unroll
  for (int tt = 0; tt < 6; ++tt)
#pragma unroll
    for (int r = 0; r < 4; ++r) {
      const int i = qw + l4 * 4 + r;
      const int j = q0 - 64 + (tb + tt) * 16 + l15;
      const int diff = i - j;
      float sv = (j >= 0 && diff >= 0 && diff < WIN) ? s[tt][r] : -3e38f;
      s[tt][r] = sv;
      rmax[r] = fmaxf(rmax[r], sv);
    }
#pragma unroll
  for (int r = 0; r < 4; ++r)
#pragma unroll
    for (int m = 1; m < 16; m <<= 1)
      rmax[r] = fmaxf(rmax[r], __shfl_xor(rmax[r], m, 64));

  float rsum[4] = {0.f, 0.f, 0.f, 0.f};
#pragma unroll
  for (int tt = 0; tt < 6; ++tt)
#pragma unroll
    for (int r = 0; r < 4; ++r) {
      float p = __expf(s[tt][r] - rmax[r]);
      s[tt][r] = p;
      rsum[r] += p;
    }
#pragma unroll
  for (int r = 0; r < 4; ++r)
#pragma unroll
    for (int m = 1; m < 16; m <<= 1)
      rsum[r] += __shfl_xor(rsum[r], m, 64);

#pragma unroll
  for (int tt = 0; tt < 6; ++tt)
#pragma unroll
    for (int r = 0; r < 4; ++r)
      Pl[w][l4 * 4 + r][(tb + tt) * 16 + l15] = (short)f2bf(s[tt][r]);

  f32x4 o[4] = {};
#pragma unroll
  for (int kq = 0; kq < 3; ++kq) {
    const int ks = (w >> 1) + kq;
    short8 ap = *(const short8*)&Pl[w][l15][ks * 32 + l4 * 8];
    int jg = q0 - 64 + ks * 32 + l4 * 8;
    if (jg < 0) jg = 0;
#pragma unroll
    for (int dt = 0; dt < 4; ++dt) {
      const int d = dt * 16 + l15;
      short8 bv = *(const short8*)&Vh[(size_t)d * NSEQ + jg];
      o[dt] = __builtin_amdgcn_mfma_f32_16x16x32_bf16(ap, bv, o[dt], 0, 0, 0);
    }
  }

  // ---- O-store bounce: normalized O -> per-wave Pl rows (done reading
  // Pl[w] in this wave; wave-synchronous) -> 2 full-row short8 stores.
#pragma unroll
  for (int r = 0; r < 4; ++r) {
    const float rinv = 1.0f / rsum[r];
#pragma unroll
    for (int dt = 0; dt < 4; ++dt)
      Pl[w][l4 * 4 + r][dt * 16 + l15] = (short)f2bf(o[dt][r] * rinv);
  }
#pragma unroll
  for (int p = 0; p < 2; ++p) {
    const int idx = p * 64 + l;
    const int row = idx >> 3;          // 0..15
    const int col = (idx & 7) * 8;     // 0..56
    *(short8*)&att[(size_t)(qw + row) * DM + h * DHEAD + col] =
        *(const short8*)&Pl[w][row][col];
  }
}

// ---------------- launch ----------------
extern "C" void kernel_launch(void* const* d_in, const int* in_sizes, int n_in,
                              void* d_out, int out_size, void* d_ws, size_t ws_size,
                              hipStream_t stream) {
  const float* x    = (const float*)d_in[0];
  const float* wqkv = (const float*)d_in[1];
  const float* bqkv = (const float*)d_in[2];
  const float* wout = (const float*)d_in[3];
  const float* bout = (const float*)d_in[4];
  float* out = (float*)d_out;

  unsigned short* ws = (unsigned short*)d_ws;
  unsigned short* xb    = ws;
  unsigned short* wqkvb = xb    + (size_t)NSEQ * DM;
  unsigned short* woutb = wqkvb + (size_t)3 * DM * DM;
  unsigned short* qb    = woutb + (size_t)DM * DM;
  unsigned short* kb    = qb    + (size_t)NSEQ * DM;
  unsigned short* vtb   = kb    + (size_t)NSEQ * DM;
  unsigned short* attb  = vtb   + (size_t)NSEQ * DM;

  cvt_all<<<8192, 256, 0, stream>>>(x, wqkv, wout, xb);

  gemm_qkv<<<32 * 8, 512, 0, stream>>>(xb, wqkvb, bqkv, qb, kb, vtb);

  attn_kernel<<<NHEAD * (NSEQ / 64), 256, 0, stream>>>(qb, kb, vtb, attb);

  gemm_op<<<64 * 8, 256, 0, stream>>>(attb, woutb, bout, out);
}

// Round 17
// 79.148 us; speedup vs baseline: 1.0155x; 1.0155x over previous
//
#include <hip/hip_runtime.h>
#include <hip/hip_bf16.h>
#include <stdint.h>
#include <stddef.h>

#define NSEQ  4096
#define DM    1024
#define NHEAD 16
#define DHEAD 64
#define WIN   64

using short8 = __attribute__((ext_vector_type(8))) short;
using f32x4  = __attribute__((ext_vector_type(4))) float;

#define GLOBAL_AS __attribute__((address_space(1)))
#define LDS_AS    __attribute__((address_space(3)))

__device__ __forceinline__ unsigned short f2bf(float f) {
  union { float f; unsigned int u; } v; v.f = f;
  unsigned int r = v.u + 0x7FFFu + ((v.u >> 16) & 1u);
  return (unsigned short)(r >> 16);
}

__device__ __forceinline__ void gload_lds16(void* lds, const void* g) {
  __builtin_amdgcn_global_load_lds((const GLOBAL_AS unsigned int*)g,
                                   (LDS_AS unsigned int*)lds, 16, 0, 0);
}

// ---------------- fused fp32 -> bf16 conversion (x | w_qkv | w_out) --------
#define NX4 1048576
#define NW4 786432
__global__ void cvt_all(const float* __restrict__ x,
                        const float* __restrict__ wqkv,
                        const float* __restrict__ wout,
                        unsigned short* __restrict__ dst) {
  int i = blockIdx.x * blockDim.x + threadIdx.x;   // group of 4 floats
  float4 f;
  if (i < NX4)            f = ((const float4*)x)[i];
  else if (i < NX4 + NW4) f = ((const float4*)wqkv)[i - NX4];
  else                    f = ((const float4*)wout)[i - (NX4 + NW4)];
  ushort4 o;
  o.x = f2bf(f.x); o.y = f2bf(f.y); o.z = f2bf(f.z); o.w = f2bf(f.w);
  ((ushort4*)dst)[i] = o;
}

// ============ QKV GEMM: 128x384 tile, BK=64, 2-phase/tile, 24 MFMA/barrier =
// Main loop unchanged from round 14 (best validated). Epilogue: LDS bounce,
// FIXED geometry: 6 groups of 64 cols (g = bn*6+gi, region = g>>4, h = g&15).
// Unified slot = 9216 shorts/group (6*9216 = 55296 <= 65536):
//   Q/K group: [128 rows][72]  (64 used; 144B rows = 9x16B, short8-aligned)
//   V   group: [64 d][144]     (128 used; transposed at write)
// Readout idx = jj*512+tid -> contiguous 1-KB wave stores (lane stride 16 B).
// Epilogue starts after the final in-loop barrier (no LDS readers remain);
// one __syncthreads between write and readout.
__global__ __launch_bounds__(512, 1)
void gemm_qkv(const unsigned short* __restrict__ A,
              const unsigned short* __restrict__ B,
              const float* __restrict__ bias,
              unsigned short* __restrict__ qo,
              unsigned short* __restrict__ ko,
              unsigned short* __restrict__ vo) {
  __shared__ short lds[65536];   // 128 KB: buf b at b*32768 {A:8192 | B:24576}

  const int bm = blockIdx.x >> 3;    // M/128 = 32
  const int bn = blockIdx.x & 7;     // N/384 = 8
  const int m0 = bm << 7, n0 = bn * 384;
  const int tid = threadIdx.x, w = tid >> 6, l = tid & 63;
  const int wr = w >> 2, wc = w & 3;
  const int l15 = l & 15, l4 = l >> 4;
  const int srow = l >> 2;
  const int skel = ((l & 3) << 3) ^ ((l >= 32) << 4);          // inv-swz global k
  const int roff = l15 * 32 + ((l4 * 8) ^ ((l15 >= 8) * 16));  // swz read off

  f32x4 acc[4][6] = {};

  auto stageA = [&](int j) {
    const int base = (j & 1) * 32768;
#pragma unroll
    for (int r = 0; r < 2; ++r) {
      const int c = r * 8 + w;
      gload_lds16(&lds[base + c * 512 + l * 8],
                  A + (size_t)(m0 + (c >> 1) * 16 + srow) * 1024
                    + (j << 6) + (c & 1) * 32 + skel);
    }
  };
  auto stageB = [&](int j, int qk) {
    const int base = (j & 1) * 32768 + 8192 + qk * 12288;
#pragma unroll
    for (int r = 0; r < 3; ++r) {
      const int c = r * 8 + w;
      gload_lds16(&lds[base + c * 512 + l * 8],
                  B + (size_t)(n0 + c * 16 + srow) * 1024
                    + (j << 6) + qk * 32 + skel);
    }
  };

  auto ldfrag = [&](short8* af, short8* bf, int buf, int qk) {
    const short* Ah = &lds[buf];
    const short* Bh = &lds[buf + 8192 + qk * 12288];
#pragma unroll
    for (int i = 0; i < 4; ++i)
      af[i] = *(const short8*)&Ah[((wr * 4 + i) * 2 + qk) * 512 + roff];
#pragma unroll
    for (int ni = 0; ni < 6; ++ni)
      bf[ni] = *(const short8*)&Bh[(wc * 6 + ni) * 512 + roff];
  };
  auto mfma24 = [&](const short8* af, const short8* bf) {
    __builtin_amdgcn_s_setprio(1);
#pragma unroll
    for (int i = 0; i < 4; ++i)
#pragma unroll
      for (int ni = 0; ni < 6; ++ni)
        acc[i][ni] = __builtin_amdgcn_mfma_f32_16x16x32_bf16(
            af[i], bf[ni], acc[i][ni], 0, 0, 0);
    __builtin_amdgcn_s_setprio(0);
  };

  // prologue
  stageA(0); stageB(0, 0); stageB(0, 1); stageB(1, 0);
  asm volatile("s_waitcnt vmcnt(3)" ::: "memory");   // Bk0(1) stays in flight
  __builtin_amdgcn_s_barrier();

  const int NT = 16;   // 1024 / 64
  short8 af[4], bf[6];
  for (int j = 0; j < NT; ++j) {
    const int buf = (j & 1) * 32768;
    // ---- p0 (qk=0) ----
    ldfrag(af, bf, buf, 0);
    if (j + 1 < NT) { stageA(j + 1); stageB(j + 1, 1); }
    __builtin_amdgcn_s_barrier();
    mfma24(af, bf);
    // ---- p1 (qk=1) ----
    ldfrag(af, bf, buf, 1);
    if (j + 2 < NT) {
      stageB(j + 2, 0);
      asm volatile("s_waitcnt vmcnt(3)" ::: "memory");  // {A,Bk1,Bk0}(j+1) in
    } else if (j + 1 < NT) {
      asm volatile("s_waitcnt vmcnt(0)" ::: "memory");
    }
    __builtin_amdgcn_s_barrier();
    mfma24(af, bf);
  }

  // ==== epilogue: LDS bounce -> coalesced vector stores (FIXED) ====
#pragma unroll
  for (int ni = 0; ni < 6; ++ni) {
    const int lc = wc * 96 + ni * 16 + l15;   // 0..383
    const int gi = lc >> 6;                   // 0..5 (uniform per wc,ni)
    const int c  = lc & 63;
    const int n  = n0 + lc;
    const float bv = bias[n];
    const int region = n >> 10;               // uniform per (wc,ni) group
    const float sc = region == 0 ? 0.125f : 1.0f;
    short* S = lds + gi * 9216;
#pragma unroll
    for (int mi = 0; mi < 4; ++mi) {
      const int lr = wr * 64 + mi * 16 + l4 * 4;
#pragma unroll
      for (int r = 0; r < 4; ++r) {
        const unsigned short hv = f2bf((acc[mi][ni][r] + bv) * sc);
        if (region < 2) S[(lr + r) * 72 + c] = (short)hv;     // [128][72]
        else            S[c * 144 + lr + r] = (short)hv;      // [64][144] ^T
      }
    }
  }
  __syncthreads();
#pragma unroll
  for (int gi = 0; gi < 6; ++gi) {
    const int g = bn * 6 + gi;            // global 64-col group, 0..47
    const int region = g >> 4;            // 0=Q, 1=K, 2=V
    const int h = g & 15;
    const short* S = lds + gi * 9216;
    if (region < 2) {
      unsigned short* dst = region == 0 ? qo : ko;
#pragma unroll
      for (int jj = 0; jj < 2; ++jj) {
        const int idx = jj * 512 + tid;   // 0..1023 = 128 rows x 8 chunks
        const int row = idx >> 3, c8 = (idx & 7) * 8;
        *(short8*)&dst[((size_t)(h * NSEQ + m0 + row)) * DHEAD + c8] =
            *(const short8*)&S[row * 72 + c8];
      }
    } else {
#pragma unroll
      for (int jj = 0; jj < 2; ++jj) {
        const int idx = jj * 512 + tid;   // 0..1023 = 64 d x 16 chunks
        const int d = idx >> 4, rc = (idx & 15) * 8;
        *(short8*)&vo[((size_t)(h * 64 + d)) * NSEQ + m0 + rc] =
            *(const short8*)&S[d * 144 + rc];
      }
    }
  }
}

// ====== out-proj GEMM: 64x128 tile, BK=64, 2-buf, 2 blocks/CU ==============
// (round-13/14 validated form)
__global__ __launch_bounds__(256)
void gemm_op(const unsigned short* __restrict__ A,
             const unsigned short* __restrict__ B,
             const float* __restrict__ bias,
             float* __restrict__ Cf) {
  __shared__ short lds[2][12288];   // 24 KB/buf: A 4096 | B 8192 shorts

  const int wg = (blockIdx.x & 7) * 64 + (blockIdx.x >> 3);  // XCD chunks
  const int bm = wg >> 3;           // 64 m-tiles (64 rows)
  const int bn = wg & 7;            // 8 n-tiles (128 cols)
  const int m0 = bm << 6, n0 = bn << 7;
  const int tid = threadIdx.x, w = tid >> 6, l = tid & 63;
  const int wr = w >> 1, wc = w & 1;
  const int l15 = l & 15, l4 = l >> 4;
  const int srow = l >> 2;
  const int skel = ((l & 3) << 3) ^ ((l >= 32) << 4);
  const int roff = l15 * 32 + ((l4 * 8) ^ ((l15 >= 8) * 16));

  f32x4 acc[2][4] = {};
  const int NT = 16;

  auto stage = [&](int t) {
    const int buf = t & 1;
    const int kb  = t << 6;
#pragma unroll
    for (int r = 0; r < 2; ++r) {          // A: 8 subtiles
      const int c = r * 4 + w;
      gload_lds16(&lds[buf][c * 512 + l * 8],
                  A + (size_t)(m0 + (c >> 1) * 16 + srow) * 1024
                    + kb + (c & 1) * 32 + skel);
    }
#pragma unroll
    for (int r = 0; r < 4; ++r) {          // B: 16 subtiles
      const int c = r * 4 + w;
      gload_lds16(&lds[buf][4096 + c * 512 + l * 8],
                  B + (size_t)(n0 + (c >> 1) * 16 + srow) * 1024
                    + kb + (c & 1) * 32 + skel);
    }
  };

  stage(0);
  for (int t = 0; t < NT; ++t) {
    __syncthreads();                    // full drain -> stage(t) visible
    if (t + 1 < NT) stage(t + 1);       // other buf (WAR-safe after barrier)
    const short* Ab = &lds[t & 1][0];
    const short* Bb = &lds[t & 1][4096];
    short8 af[2][2], bf[4][2];
#pragma unroll
    for (int mi = 0; mi < 2; ++mi)
#pragma unroll
      for (int kk = 0; kk < 2; ++kk)
        af[mi][kk] = *(const short8*)&Ab[((wr * 2 + mi) * 2 + kk) * 512 + roff];
#pragma unroll
    for (int ni = 0; ni < 4; ++ni)
#pragma unroll
      for (int kk = 0; kk < 2; ++kk)
        bf[ni][kk] = *(const short8*)&Bb[((wc * 4 + ni) * 2 + kk) * 512 + roff];
    __builtin_amdgcn_s_setprio(1);
#pragma unroll
    for (int kk = 0; kk < 2; ++kk)
#pragma unroll
      for (int mi = 0; mi < 2; ++mi)
#pragma unroll
        for (int ni = 0; ni < 4; ++ni)
          acc[mi][ni] = __builtin_amdgcn_mfma_f32_16x16x32_bf16(
              af[mi][kk], bf[ni][kk], acc[mi][ni], 0, 0, 0);
    __builtin_amdgcn_s_setprio(0);
  }

#pragma unroll
  for (int ni = 0; ni < 4; ++ni) {
    const int n  = n0 + wc * 64 + ni * 16 + l15;
    const float bv = bias[n];
#pragma unroll
    for (int mi = 0; mi < 2; ++mi) {
      const int mb = m0 + wr * 32 + mi * 16 + l4 * 4;
#pragma unroll
      for (int r = 0; r < 4; ++r)
        Cf[(size_t)(mb + r) * DM + n] = acc[mi][ni][r] + bv;
    }
  }
}

// ---------------- windowed causal attention: 6-tile window trim ------------
// (round-9/14 validated form)
__global__ __launch_bounds__(256)
void attn_kernel(const unsigned short* __restrict__ Qb,
                 const unsigned short* __restrict__ Kb,
                 const unsigned short* __restrict__ Vt,
                 unsigned short* __restrict__ att) {
  __shared__ short Pl[4][16][136];
  const int h  = blockIdx.x >> 6;
  const int q0 = (blockIdx.x & 63) << 6;
  const int w  = threadIdx.x >> 6;
  const int l  = threadIdx.x & 63;
  const int l15 = l & 15, l4 = l >> 4;
  const int qw = q0 + w * 16;
  const int tb = w & ~1;

  const unsigned short* Qh = Qb + (size_t)h * NSEQ * DHEAD;
  const unsigned short* Kh = Kb + (size_t)h * NSEQ * DHEAD;
  const unsigned short* Vh = Vt + (size_t)h * DHEAD * NSEQ;

  short8 aq[2];
  {
    const int qrow = qw + l15;
    aq[0] = *(const short8*)&Qh[(size_t)qrow * DHEAD + l4 * 8];
    aq[1] = *(const short8*)&Qh[(size_t)qrow * DHEAD + 32 + l4 * 8];
  }

  f32x4 s[6] = {};
#pragma unroll
  for (int tt = 0; tt < 6; ++tt) {
    int j  = q0 - 64 + (tb + tt) * 16 + l15;
    int jc = j < 0 ? 0 : j;
    short8 b0 = *(const short8*)&Kh[(size_t)jc * DHEAD + l4 * 8];
    short8 b1 = *(const short8*)&Kh[(size_t)jc * DHEAD + 32 + l4 * 8];
    s[tt] = __builtin_amdgcn_mfma_f32_16x16x32_bf16(aq[0], b0, s[tt], 0, 0, 0);
    s[tt] = __builtin_amdgcn_mfma_f32_16x16x32_bf16(aq[1], b1, s[tt], 0, 0, 0);
  }

  float rmax[4] = {-3e38f, -3e38f, -3e38f, -3e38f};
#pragma unroll
  for (int tt = 0; tt < 6; ++tt)
#pragma unroll
    for (int r = 0; r < 4; ++r) {
      const int i = qw + l4 * 4 + r;
      const int j = q0 - 64 + (tb + tt) * 16 + l15;
      const int diff = i - j;
      float sv = (j >= 0 && diff >= 0 && diff < WIN) ? s[tt][r] : -3e38f;
      s[tt][r] = sv;
      rmax[r] = fmaxf(rmax[r], sv);
    }
#pragma unroll
  for (int r = 0; r < 4; ++r)
#pragma unroll
    for (int m = 1; m < 16; m <<= 1)
      rmax[r] = fmaxf(rmax[r], __shfl_xor(rmax[r], m, 64));

  float rsum[4] = {0.f, 0.f, 0.f, 0.f};
#pragma unroll
  for (int tt = 0; tt < 6; ++tt)
#pragma unroll
    for (int r = 0; r < 4; ++r) {
      float p = __expf(s[tt][r] - rmax[r]);
      s[tt][r] = p;
      rsum[r] += p;
    }
#pragma unroll
  for (int r = 0; r < 4; ++r)
#pragma unroll
    for (int m = 1; m < 16; m <<= 1)
      rsum[r] += __shfl_xor(rsum[r], m, 64);

#pragma unroll
  for (int tt = 0; tt < 6; ++tt)
#pragma unroll
    for (int r = 0; r < 4; ++r)
      Pl[w][l4 * 4 + r][(tb + tt) * 16 + l15] = (short)f2bf(s[tt][r]);

  f32x4 o[4] = {};
#pragma unroll
  for (int kq = 0; kq < 3; ++kq) {
    const int ks = (w >> 1) + kq;
    short8 ap = *(const short8*)&Pl[w][l15][ks * 32 + l4 * 8];
    int jg = q0 - 64 + ks * 32 + l4 * 8;
    if (jg < 0) jg = 0;
#pragma unroll
    for (int dt = 0; dt < 4; ++dt) {
      const int d = dt * 16 + l15;
      short8 bv = *(const short8*)&Vh[(size_t)d * NSEQ + jg];
      o[dt] = __builtin_amdgcn_mfma_f32_16x16x32_bf16(ap, bv, o[dt], 0, 0, 0);
    }
  }

#pragma unroll
  for (int r = 0; r < 4; ++r) {
    const float rinv = 1.0f / rsum[r];
    const int m = qw + l4 * 4 + r;
#pragma unroll
    for (int dt = 0; dt < 4; ++dt)
      att[(size_t)m * DM + h * DHEAD + dt * 16 + l15] = f2bf(o[dt][r] * rinv);
  }
}

// ---------------- launch ----------------
extern "C" void kernel_launch(void* const* d_in, const int* in_sizes, int n_in,
                              void* d_out, int out_size, void* d_ws, size_t ws_size,
                              hipStream_t stream) {
  const float* x    = (const float*)d_in[0];
  const float* wqkv = (const float*)d_in[1];
  const float* bqkv = (const float*)d_in[2];
  const float* wout = (const float*)d_in[3];
  const float* bout = (const float*)d_in[4];
  float* out = (float*)d_out;

  unsigned short* ws = (unsigned short*)d_ws;
  unsigned short* xb    = ws;
  unsigned short* wqkvb = xb    + (size_t)NSEQ * DM;
  unsigned short* woutb = wqkvb + (size_t)3 * DM * DM;
  unsigned short* qb    = woutb + (size_t)DM * DM;
  unsigned short* kb    = qb    + (size_t)NSEQ * DM;
  unsigned short* vtb   = kb    + (size_t)NSEQ * DM;
  unsigned short* attb  = vtb   + (size_t)NSEQ * DM;

  cvt_all<<<8192, 256, 0, stream>>>(x, wqkv, wout, xb);

  gemm_qkv<<<32 * 8, 512, 0, stream>>>(xb, wqkvb, bqkv, qb, kb, vtb);

  attn_kernel<<<NHEAD * (NSEQ / 64), 256, 0, stream>>>(qb, kb, vtb, attb);

  gemm_op<<<64 * 8, 256, 0, stream>>>(attb, woutb, bout, out);
}